// Round 6
// baseline (684.828 us; speedup 1.0000x reference)
//
#include <hip/hip_runtime.h>

typedef unsigned int u32;

// GCN, 2-layer (16->16 relu, 16->8), DGL GraphConv norm='both', self-loops.
// N = 100000 nodes, E = 3.2M edges, f32, edge_index int32.
// dst-bucketed counting sort (once) -> atomic-free-in-global aggregation.
// Round 6: src-TILED aggregation passes. The packed edge word carries src in
// bits 0..16; (w>>14)&7 = src tile (16384 nodes = 1MB of h). Agg sweeps its
// bucket 7x, pass t touching only tile-t sources -> gathers hit per-XCD L2
// (live window ~1-2MB << 4MB). Kills the distinct-line MSHR bottleneck that
// pinned rounds 3-5 at ~345us regardless of ILP shape.

constexpr int F1 = 16;
constexpr int F2 = 8;
constexpr int HIST_N   = 100000;        // specialized node count
constexpr int HIST_U32 = HIST_N / 4;    // 25000 packed-u8 words
constexpr int NB_HIST  = 256;           // one hist block per CU
constexpr int RB       = 128;           // nodes per dst bucket
constexpr int NBUCK    = (HIST_N + RB - 1) / RB;  // 782
constexpr int P2B      = 512;           // partition/count blocks
constexpr int NT       = 7;             // src tiles: 99999>>14 = 6 -> tiles 0..6

// ---- src-degree: LDS packed-u8 histogram + byte-sum merge -> norm ----

__global__ void __launch_bounds__(256) hist_kernel(const int* __restrict__ idx,
                                                   u32* __restrict__ partial,
                                                   int nE, int per_block) {
    __shared__ u32 h[HIST_U32];
    for (int i = threadIdx.x; i < HIST_U32; i += 256) h[i] = 0u;
    __syncthreads();
    const int beg = blockIdx.x * per_block;
    const int end = min(nE, beg + per_block);
    for (int base = beg; base < end; base += 256 * 4) {
        int i = base + threadIdx.x * 4;
        if (i + 3 < end) {
            int4 v = *reinterpret_cast<const int4*>(idx + i);
            atomicAdd(&h[v.x >> 2], 1u << ((v.x & 3) << 3));
            atomicAdd(&h[v.y >> 2], 1u << ((v.y & 3) << 3));
            atomicAdd(&h[v.z >> 2], 1u << ((v.z & 3) << 3));
            atomicAdd(&h[v.w >> 2], 1u << ((v.w & 3) << 3));
        } else {
#pragma unroll
            for (int k = 0; k < 4; ++k)
                if (i + k < end) {
                    int v = idx[i + k];
                    atomicAdd(&h[v >> 2], 1u << ((v & 3) << 3));
                }
        }
    }
    __syncthreads();
    u32* out = partial + (size_t)blockIdx.x * HIST_U32;
    for (int i = threadIdx.x; i < HIST_U32; i += 256) out[i] = h[i];
}

__global__ void __launch_bounds__(256) merge_norm_kernel(const u32* __restrict__ partial,
                                                         float* __restrict__ norm) {
    int t = blockIdx.x * 256 + threadIdx.x;
    if (t >= HIST_U32) return;
    u32 s0 = 0, s1 = 0, s2 = 0, s3 = 0;
    const u32* p = partial + t;
    for (int b = 0; b < NB_HIST; ++b) {
        u32 v = p[(size_t)b * HIST_U32];
        s0 += v & 0xffu; s1 += (v >> 8) & 0xffu;
        s2 += (v >> 16) & 0xffu; s3 += v >> 24;
    }
    float4 o = make_float4(rsqrtf(1.f + (float)s0), rsqrtf(1.f + (float)s1),
                           rsqrtf(1.f + (float)s2), rsqrtf(1.f + (float)s3));
    *reinterpret_cast<float4*>(norm + (size_t)t * 4) = o;
}

// ---- dst-bucket counting sort ----

__global__ void __launch_bounds__(256) bucket_count_kernel(const int* __restrict__ dst,
                                                           u32* __restrict__ bcnt, int nE) {
    __shared__ u32 c[NBUCK];
    for (int j = threadIdx.x; j < NBUCK; j += 256) c[j] = 0;
    __syncthreads();
    for (int i = blockIdx.x * 256 + threadIdx.x; i < nE; i += 256 * P2B)
        atomicAdd(&c[dst[i] >> 7], 1u);
    __syncthreads();
    for (int j = threadIdx.x; j < NBUCK; j += 256)
        if (c[j]) atomicAdd(&bcnt[j], c[j]);
}

__global__ void __launch_bounds__(1024) bucket_scan_kernel(const u32* __restrict__ bcnt,
                                                           u32* __restrict__ bbase,
                                                           u32* __restrict__ bcur) {
    __shared__ u32 s[1024];
    int t = threadIdx.x;
    u32 v = (t < NBUCK) ? bcnt[t] : 0;
    s[t] = v;
    __syncthreads();
    for (int off = 1; off < 1024; off <<= 1) {
        u32 a = (t >= off) ? s[t - off] : 0;
        __syncthreads();
        s[t] += a;
        __syncthreads();
    }
    if (t < NBUCK) {
        u32 ex = s[t] - v;
        bbase[t] = ex;
        bcur[t] = ex;
        if (t == NBUCK - 1) bbase[NBUCK] = s[t];
    }
}

// pack: (dst_local<<17) | src   (src < 2^17, dst_local < 128)
__global__ void __launch_bounds__(256) partition_kernel(const int* __restrict__ src,
                                                        const int* __restrict__ dst,
                                                        u32* __restrict__ part,
                                                        u32* __restrict__ bcur,
                                                        int nE, int per_block) {
    __shared__ u32 cnt[NBUCK];
    __shared__ u32 gb[NBUCK];
    for (int j = threadIdx.x; j < NBUCK; j += 256) cnt[j] = 0;
    __syncthreads();
    const int beg = blockIdx.x * per_block;
    const int end = min(nE, beg + per_block);
    for (int i = beg + threadIdx.x; i < end; i += 256)
        atomicAdd(&cnt[dst[i] >> 7], 1u);
    __syncthreads();
    for (int j = threadIdx.x; j < NBUCK; j += 256) {
        u32 c = cnt[j];
        gb[j] = c ? atomicAdd(&bcur[j], c) : 0u;
        cnt[j] = 0;
    }
    __syncthreads();
    for (int i = beg + threadIdx.x; i < end; i += 256) {
        int d = dst[i];
        int b = d >> 7;
        u32 r = atomicAdd(&cnt[b], 1u);
        part[gb[b] + r] = ((u32)(d & 127) << 17) | (u32)src[i];
    }
}

// norm_dst from partitioned edges: per-bucket dst_local counts
__global__ void __launch_bounds__(256) norm_dst_kernel(const u32* __restrict__ part,
                                                       const u32* __restrict__ bbase,
                                                       float* __restrict__ norm_dst, int n) {
    __shared__ u32 c[RB];
    if (threadIdx.x < RB) c[threadIdx.x] = 0;
    __syncthreads();
    u32 beg = bbase[blockIdx.x], end = bbase[blockIdx.x + 1];
    for (u32 j = beg + threadIdx.x; j < end; j += 256)
        atomicAdd(&c[part[j] >> 17], 1u);
    __syncthreads();
    if (threadIdx.x < RB) {
        int node = blockIdx.x * RB + threadIdx.x;
        if (node < n) norm_dst[node] = rsqrtf(1.f + (float)c[threadIdx.x]);
    }
}

// ---- aggregation, src-tiled passes + fused combine epilogue ----
// One 512-thread block per bucket. F consecutive lanes own an edge (gather is
// line-coalesced). NT passes over the bucket's edges; pass t accumulates only
// edges with src in tile t -> live gather window ~1-2MB, L2-resident.
template <int F, bool RELU>
__global__ void __launch_bounds__(512) agg_fused_kernel(
        const u32* __restrict__ part, const u32* __restrict__ bbase,
        const float* __restrict__ h, const float* __restrict__ norm_dst,
        const float* __restrict__ bias, float* __restrict__ out, int n) {
    __shared__ float acc[RB * (F + 1)];   // +1 pad decorrelates banks
    for (int j = threadIdx.x; j < RB * (F + 1); j += 512) acc[j] = 0.f;
    __syncthreads();
    const int b = blockIdx.x;
    const u32 beg = bbase[b], end = bbase[b + 1];
    const int g = threadIdx.x / F;        // edge slot
    const int f = threadIdx.x % F;        // feature
    const int step = 512 / F;             // 32 (F=16) / 64 (F=8)

    for (u32 t = 0; t < NT; ++t) {
        for (u32 j = beg + g; j < end; j += 4 * step) {
            u32 j1 = j + step, j2 = j + 2 * step, j3 = j + 3 * step;
            // sentinel 0xFFFFFFFF -> tile field = 7 -> never matches t (t<=6)
            u32 w0 = part[j];
            u32 w1 = (j1 < end) ? part[j1] : 0xFFFFFFFFu;
            u32 w2 = (j2 < end) ? part[j2] : 0xFFFFFFFFu;
            u32 w3 = (j3 < end) ? part[j3] : 0xFFFFFFFFu;
            bool m0 = ((w0 >> 14) & 7u) == t;
            bool m1 = ((w1 >> 14) & 7u) == t;
            bool m2 = ((w2 >> 14) & 7u) == t;
            bool m3 = ((w3 >> 14) & 7u) == t;
            float v0 = m0 ? h[(size_t)(w0 & 0x1FFFFu) * F + f] : 0.f;
            float v1 = m1 ? h[(size_t)(w1 & 0x1FFFFu) * F + f] : 0.f;
            float v2 = m2 ? h[(size_t)(w2 & 0x1FFFFu) * F + f] : 0.f;
            float v3 = m3 ? h[(size_t)(w3 & 0x1FFFFu) * F + f] : 0.f;
            if (m0) atomicAdd(&acc[(w0 >> 17) * (F + 1) + f], v0);
            if (m1) atomicAdd(&acc[(w1 >> 17) * (F + 1) + f], v1);
            if (m2) atomicAdd(&acc[(w2 >> 17) * (F + 1) + f], v2);
            if (m3) atomicAdd(&acc[(w3 >> 17) * (F + 1) + f], v3);
        }
    }
    __syncthreads();
    const int base_out = b * RB * F;   // contiguous: node*F+f = base_out + idx
    for (int idx = threadIdx.x; idx < RB * F; idx += 512) {
        int gidx = base_out + idx;
        if (gidx < n * F) {
            int dl = idx / F, ff = idx - dl * F;
            int node = b * RB + dl;
            float v = (acc[dl * (F + 1) + ff] + h[gidx]) * norm_dst[node] + bias[ff];
            if (RELU) v = fmaxf(v, 0.f);
            out[gidx] = v;
        }
    }
}

// ---- dense transforms ----

__global__ void xw16_kernel(const float* __restrict__ x, const float* __restrict__ W,
                            const float* __restrict__ norm_src,
                            float* __restrict__ h, int n) {
    __shared__ float Ws[256];
    int t = threadIdx.x;
    if (t < 256) Ws[t] = W[t];
    __syncthreads();
    int i = blockIdx.x * blockDim.x + t;
    if (i >= n) return;
    float xi[16];
    const float4* xp = reinterpret_cast<const float4*>(x + (size_t)i * 16);
    float4 v;
    v = xp[0]; xi[0]=v.x; xi[1]=v.y; xi[2]=v.z; xi[3]=v.w;
    v = xp[1]; xi[4]=v.x; xi[5]=v.y; xi[6]=v.z; xi[7]=v.w;
    v = xp[2]; xi[8]=v.x; xi[9]=v.y; xi[10]=v.z; xi[11]=v.w;
    v = xp[3]; xi[12]=v.x; xi[13]=v.y; xi[14]=v.z; xi[15]=v.w;
    float ns = norm_src[i];
    float o[16];
#pragma unroll
    for (int j = 0; j < 16; ++j) {
        float acc = 0.f;
#pragma unroll
        for (int k = 0; k < 16; ++k) acc = fmaf(xi[k], Ws[k * 16 + j], acc);
        o[j] = acc * ns;
    }
    float4* hp = reinterpret_cast<float4*>(h + (size_t)i * 16);
    hp[0] = make_float4(o[0], o[1], o[2], o[3]);
    hp[1] = make_float4(o[4], o[5], o[6], o[7]);
    hp[2] = make_float4(o[8], o[9], o[10], o[11]);
    hp[3] = make_float4(o[12], o[13], o[14], o[15]);
}

__global__ void xw8_kernel(const float* __restrict__ x, const float* __restrict__ W,
                           const float* __restrict__ norm_src,
                           float* __restrict__ h, int n) {
    __shared__ float Ws[128];
    int t = threadIdx.x;
    if (t < 128) Ws[t] = W[t];
    __syncthreads();
    int i = blockIdx.x * blockDim.x + t;
    if (i >= n) return;
    float xi[16];
    const float4* xp = reinterpret_cast<const float4*>(x + (size_t)i * 16);
    float4 v;
    v = xp[0]; xi[0]=v.x; xi[1]=v.y; xi[2]=v.z; xi[3]=v.w;
    v = xp[1]; xi[4]=v.x; xi[5]=v.y; xi[6]=v.z; xi[7]=v.w;
    v = xp[2]; xi[8]=v.x; xi[9]=v.y; xi[10]=v.z; xi[11]=v.w;
    v = xp[3]; xi[12]=v.x; xi[13]=v.y; xi[14]=v.z; xi[15]=v.w;
    float ns = norm_src[i];
    float o[8];
#pragma unroll
    for (int j = 0; j < 8; ++j) {
        float acc = 0.f;
#pragma unroll
        for (int k = 0; k < 16; ++k) acc = fmaf(xi[k], Ws[k * 8 + j], acc);
        o[j] = acc * ns;
    }
    float4* hp = reinterpret_cast<float4*>(h + (size_t)i * 8);
    hp[0] = make_float4(o[0], o[1], o[2], o[3]);
    hp[1] = make_float4(o[4], o[5], o[6], o[7]);
}

// out = ((agg + h_self) * norm_dst + b), optional relu  (fallback path only)
template <int F, bool RELU>
__global__ void combine_kernel(const float* __restrict__ agg, const float* __restrict__ h,
                               const float* __restrict__ norm_dst,
                               const float* __restrict__ b,
                               float* __restrict__ out, int n) {
    int t = blockIdx.x * 256 + threadIdx.x;
    if (t >= n * F) return;
    int i = t / F;
    int f = t % F;
    float v = (agg[t] + h[t]) * norm_dst[i] + b[f];
    if (RELU) v = fmaxf(v, 0.f);
    out[t] = v;
}

// ---- fallback (n != 100000 or small ws): scattered-atomic path ----

__global__ void init_deg_kernel(float* __restrict__ a, float* __restrict__ b, int n) {
    int i = blockIdx.x * 256 + threadIdx.x;
    if (i < n) { a[i] = 1.0f; b[i] = 1.0f; }
}
__global__ void count_deg_kernel(const int* __restrict__ src, const int* __restrict__ dst,
                                 float* __restrict__ dego, float* __restrict__ degi, int nE) {
    int e = blockIdx.x * 256 + threadIdx.x;
    if (e < nE) { atomicAdd(dego + src[e], 1.0f); atomicAdd(degi + dst[e], 1.0f); }
}
__global__ void rsqrt_kernel(float* __restrict__ a, float* __restrict__ b, int n) {
    int i = blockIdx.x * 256 + threadIdx.x;
    if (i < n) { a[i] = rsqrtf(a[i]); b[i] = rsqrtf(b[i]); }
}
template <int F>
__global__ void scatter_kernel(const int* __restrict__ src, const int* __restrict__ dst,
                               const float* __restrict__ h, float* __restrict__ agg,
                               int nE) {
    long long t = (long long)blockIdx.x * blockDim.x + threadIdx.x;
    if (t >= (long long)nE * F) return;
    int e = (int)(t / F);
    int f = (int)(t % F);
    atomicAdd(agg + (size_t)dst[e] * F + f, h[(size_t)src[e] * F + f]);
}

extern "C" void kernel_launch(void* const* d_in, const int* in_sizes, int n_in,
                              void* d_out, int out_size, void* d_ws, size_t ws_size,
                              hipStream_t stream) {
    const float* x  = (const float*)d_in[0];
    const float* W1 = (const float*)d_in[1];
    const float* b1 = (const float*)d_in[2];
    const float* W2 = (const float*)d_in[3];
    const float* b2 = (const float*)d_in[4];
    const int*   ei = (const int*)d_in[5];

    const int n  = in_sizes[0] / F1;   // 100000
    const int nE = in_sizes[5] / 2;    // 3200000
    const int* src = ei;
    const int* dst = ei + nE;

    const size_t na = ((size_t)n + 63) & ~(size_t)63;
    const int B = 256;
    dim3 blk(B);
    int gN   = (int)((n + B - 1) / B);
    int gNF1 = (int)((n * (size_t)F1 + B - 1) / B);
    int gNF2 = (int)((n * (size_t)F2 + B - 1) / B);

    // fast-path workspace layout
    float* norm_src = (float*)d_ws;                  // [na]
    float* norm_dst = norm_src + na;                 // [na]
    u32*   bbase    = (u32*)(norm_dst + na);         // [1024]
    u32*   bcur     = bbase + 1024;                  // [1024]
    u32*   bcnt     = bcur + 1024;                   // [1024]
    u32*   part     = bcnt + 1024;                   // [nE]
    float* bufA     = (float*)(part + nE);           // [na*16]
    float* bufB     = bufA + na * F1;                // [na*16]
    u32*   partial  = part;                          // NB_HIST*HIST_U32 overlays part+buf
    size_t need = ((size_t)2 * na + 3 * 1024 + (size_t)nE + 32 * na) * 4;
    size_t need_hist = ((size_t)2 * na + 3 * 1024) * 4 + (size_t)NB_HIST * HIST_U32 * 4;
    if (need_hist > need) need = need_hist;

    if (n == HIST_N && ws_size >= need) {
        int per_hist = (nE + NB_HIST - 1) / NB_HIST;
        int per_p2   = (nE + P2B - 1) / P2B;
        int gM = (HIST_U32 + B - 1) / B;

        // norms (src via histogram; dst later from partition)
        hist_kernel<<<NB_HIST, blk, 0, stream>>>(src, partial, nE, per_hist);
        merge_norm_kernel<<<gM, blk, 0, stream>>>(partial, norm_src);

        // bucket counting sort of edges by dst
        hipMemsetAsync(bcnt, 0, NBUCK * sizeof(u32), stream);
        bucket_count_kernel<<<P2B, blk, 0, stream>>>(dst, bcnt, nE);
        bucket_scan_kernel<<<1, 1024, 0, stream>>>(bcnt, bbase, bcur);
        partition_kernel<<<P2B, blk, 0, stream>>>(src, dst, part, bcur, nE, per_p2);
        norm_dst_kernel<<<NBUCK, blk, 0, stream>>>(part, bbase, norm_dst, n);

        // layer 1: h1' = xW1*norm_src; out1 = relu((A^T h1' + h1')*norm_dst + b1)
        xw16_kernel<<<gN, blk, 0, stream>>>(x, W1, norm_src, bufA, n);
        agg_fused_kernel<F1, true><<<NBUCK, dim3(512), 0, stream>>>(
            part, bbase, bufA, norm_dst, b1, bufB, n);

        // layer 2
        xw8_kernel<<<gN, blk, 0, stream>>>(bufB, W2, norm_src, bufA, n);
        agg_fused_kernel<F2, false><<<NBUCK, dim3(512), 0, stream>>>(
            part, bbase, bufA, norm_dst, b2, (float*)d_out, n);
    } else {
        // fallback: scattered atomics (fits 13.7 MB ws)
        float* fnorm_src = (float*)d_ws;
        float* fnorm_dst = fnorm_src + na;
        float* fbufA     = fnorm_dst + na;
        float* fbufB     = fbufA + na * F1;
        int gE   = (nE + B - 1) / B;
        int gEF1 = (int)(((long long)nE * F1 + B - 1) / B);
        int gEF2 = (int)(((long long)nE * F2 + B - 1) / B);
        init_deg_kernel<<<gN, blk, 0, stream>>>(fnorm_src, fnorm_dst, n);
        count_deg_kernel<<<gE, blk, 0, stream>>>(src, dst, fnorm_src, fnorm_dst, nE);
        rsqrt_kernel<<<gN, blk, 0, stream>>>(fnorm_src, fnorm_dst, n);
        xw16_kernel<<<gN, blk, 0, stream>>>(x, W1, fnorm_src, fbufA, n);
        hipMemsetAsync(fbufB, 0, (size_t)n * F1 * sizeof(float), stream);
        scatter_kernel<F1><<<gEF1, blk, 0, stream>>>(src, dst, fbufA, fbufB, nE);
        combine_kernel<F1, true><<<gNF1, blk, 0, stream>>>(fbufB, fbufA, fnorm_dst, b1, fbufB, n);
        xw8_kernel<<<gN, blk, 0, stream>>>(fbufB, W2, fnorm_src, fbufA, n);
        hipMemsetAsync(fbufB, 0, (size_t)n * F2 * sizeof(float), stream);
        scatter_kernel<F2><<<gEF2, blk, 0, stream>>>(src, dst, fbufA, fbufB, nE);
        combine_kernel<F2, false><<<gNF2, blk, 0, stream>>>(fbufB, fbufA, fnorm_dst, b2,
                                                            (float*)d_out, n);
    }
}

// Round 7
// 493.360 us; speedup vs baseline: 1.3881x; 1.3881x over previous
//
#include <hip/hip_runtime.h>

typedef unsigned int u32;

// GCN, 2-layer (16->16 relu, 16->8), DGL GraphConv norm='both', self-loops.
// N = 100000 nodes, E = 3.2M edges, f32, edge_index int32.
// Round 7: src-bucketed counting sort (once) -> global-atomic scatter with
// L1/L2-resident gathers (8KB src windows), XCD-chunked block swizzle,
// fire-and-forget atomics. LDS-accumulated agg (rounds 3-6, ~345us) replaced
// by the empirically 2x-faster atomic scatter (round 2: 162us), now with
// locality fixed.

constexpr int F1 = 16;
constexpr int F2 = 8;
constexpr int HIST_N   = 100000;        // specialized node count
constexpr int HIST_U32 = HIST_N / 4;    // 25000 packed-u8 words
constexpr int NB_HIST  = 256;           // one hist block per CU
constexpr int RB       = 128;           // nodes per src bucket
constexpr int NBUCK    = (HIST_N + RB - 1) / RB;  // 782
constexpr int P2B      = 512;           // partition/count blocks
constexpr int SCB      = 2048;          // scatter blocks (divisible by 8)

// ---- dst-degree: LDS packed-u8 histogram + byte-sum merge -> norm_dst ----

__global__ void __launch_bounds__(256) hist_kernel(const int* __restrict__ idx,
                                                   u32* __restrict__ partial,
                                                   int nE, int per_block) {
    __shared__ u32 h[HIST_U32];
    for (int i = threadIdx.x; i < HIST_U32; i += 256) h[i] = 0u;
    __syncthreads();
    const int beg = blockIdx.x * per_block;
    const int end = min(nE, beg + per_block);
    for (int base = beg; base < end; base += 256 * 4) {
        int i = base + threadIdx.x * 4;
        if (i + 3 < end) {
            int4 v = *reinterpret_cast<const int4*>(idx + i);
            atomicAdd(&h[v.x >> 2], 1u << ((v.x & 3) << 3));
            atomicAdd(&h[v.y >> 2], 1u << ((v.y & 3) << 3));
            atomicAdd(&h[v.z >> 2], 1u << ((v.z & 3) << 3));
            atomicAdd(&h[v.w >> 2], 1u << ((v.w & 3) << 3));
        } else {
#pragma unroll
            for (int k = 0; k < 4; ++k)
                if (i + k < end) {
                    int v = idx[i + k];
                    atomicAdd(&h[v >> 2], 1u << ((v & 3) << 3));
                }
        }
    }
    __syncthreads();
    u32* out = partial + (size_t)blockIdx.x * HIST_U32;
    for (int i = threadIdx.x; i < HIST_U32; i += 256) out[i] = h[i];
}

__global__ void __launch_bounds__(256) merge_norm_kernel(const u32* __restrict__ partial,
                                                         float* __restrict__ norm) {
    int t = blockIdx.x * 256 + threadIdx.x;
    if (t >= HIST_U32) return;
    u32 s0 = 0, s1 = 0, s2 = 0, s3 = 0;
    const u32* p = partial + t;
    for (int b = 0; b < NB_HIST; ++b) {
        u32 v = p[(size_t)b * HIST_U32];
        s0 += v & 0xffu; s1 += (v >> 8) & 0xffu;
        s2 += (v >> 16) & 0xffu; s3 += v >> 24;
    }
    float4 o = make_float4(rsqrtf(1.f + (float)s0), rsqrtf(1.f + (float)s1),
                           rsqrtf(1.f + (float)s2), rsqrtf(1.f + (float)s3));
    *reinterpret_cast<float4*>(norm + (size_t)t * 4) = o;
}

// ---- src-bucket counting sort ----

__global__ void __launch_bounds__(256) bucket_count_kernel(const int* __restrict__ src,
                                                           u32* __restrict__ bcnt, int nE) {
    __shared__ u32 c[NBUCK];
    for (int j = threadIdx.x; j < NBUCK; j += 256) c[j] = 0;
    __syncthreads();
    for (int i = blockIdx.x * 256 + threadIdx.x; i < nE; i += 256 * P2B)
        atomicAdd(&c[src[i] >> 7], 1u);
    __syncthreads();
    for (int j = threadIdx.x; j < NBUCK; j += 256)
        if (c[j]) atomicAdd(&bcnt[j], c[j]);
}

__global__ void __launch_bounds__(1024) bucket_scan_kernel(const u32* __restrict__ bcnt,
                                                           u32* __restrict__ bbase,
                                                           u32* __restrict__ bcur) {
    __shared__ u32 s[1024];
    int t = threadIdx.x;
    u32 v = (t < NBUCK) ? bcnt[t] : 0;
    s[t] = v;
    __syncthreads();
    for (int off = 1; off < 1024; off <<= 1) {
        u32 a = (t >= off) ? s[t - off] : 0;
        __syncthreads();
        s[t] += a;
        __syncthreads();
    }
    if (t < NBUCK) {
        u32 ex = s[t] - v;
        bbase[t] = ex;
        bcur[t] = ex;
        if (t == NBUCK - 1) bbase[NBUCK] = s[t];
    }
}

// pack: (src_local<<17) | dst   (dst < 2^17, src_local < 128)
__global__ void __launch_bounds__(256) partition_kernel(const int* __restrict__ src,
                                                        const int* __restrict__ dst,
                                                        u32* __restrict__ part,
                                                        u32* __restrict__ bcur,
                                                        int nE, int per_block) {
    __shared__ u32 cnt[NBUCK];
    __shared__ u32 gb[NBUCK];
    for (int j = threadIdx.x; j < NBUCK; j += 256) cnt[j] = 0;
    __syncthreads();
    const int beg = blockIdx.x * per_block;
    const int end = min(nE, beg + per_block);
    for (int i = beg + threadIdx.x; i < end; i += 256)
        atomicAdd(&cnt[src[i] >> 7], 1u);
    __syncthreads();
    for (int j = threadIdx.x; j < NBUCK; j += 256) {
        u32 c = cnt[j];
        gb[j] = c ? atomicAdd(&bcur[j], c) : 0u;
        cnt[j] = 0;
    }
    __syncthreads();
    for (int i = beg + threadIdx.x; i < end; i += 256) {
        int s = src[i];
        int b = s >> 7;
        u32 r = atomicAdd(&cnt[b], 1u);
        part[gb[b] + r] = ((u32)(s & 127) << 17) | (u32)dst[i];
    }
}

// norm_src from partitioned edges: per-bucket src_local counts
__global__ void __launch_bounds__(256) norm_src_kernel(const u32* __restrict__ part,
                                                       const u32* __restrict__ bbase,
                                                       float* __restrict__ norm_src, int n) {
    __shared__ u32 c[RB];
    if (threadIdx.x < RB) c[threadIdx.x] = 0;
    __syncthreads();
    u32 beg = bbase[blockIdx.x], end = bbase[blockIdx.x + 1];
    for (u32 j = beg + threadIdx.x; j < end; j += 256)
        atomicAdd(&c[part[j] >> 17], 1u);
    __syncthreads();
    if (threadIdx.x < RB) {
        int node = blockIdx.x * RB + threadIdx.x;
        if (node < n) norm_src[node] = rsqrtf(1.f + (float)c[threadIdx.x]);
    }
}

// ---- scatter: gather h[src] (L1/L2-hot, src-bucketed order), global atomicAdd
// to agg[dst]. Grid-strided contiguous ranges + XCD-bijective block swizzle so
// each XCD owns a contiguous 1/8 of the src-buckets. Bucket id for each edge
// recovered by 10-step bisect over LDS-cached bbase.
template <int F>
__global__ void __launch_bounds__(256) scatter_bucketed_kernel(
        const u32* __restrict__ part, const u32* __restrict__ bbase_g,
        const float* __restrict__ h, float* __restrict__ agg, int nE) {
    __shared__ u32 bb[NBUCK + 1];
    for (int i = threadIdx.x; i < NBUCK + 1; i += 256) bb[i] = bbase_g[i];
    __syncthreads();
    // bijective XCD swizzle (m204): chunk the grid so XCD k gets contiguous blocks
    const int nb = (int)gridDim.x;
    const int q = nb / 8, r = nb % 8;
    const int x = (int)blockIdx.x % 8, ix = (int)blockIdx.x / 8;
    const int sb = (x < r ? x * (q + 1) : r * (q + 1) + (x - r) * q) + ix;

    const long long total = (long long)nE * F;
    const long long per = (total + nb - 1) / nb;
    const long long beg = (long long)sb * per;
    const long long end = (beg + per < total) ? beg + per : total;
    const int fshift = (F == 16) ? 4 : 3;

    for (long long t = beg + threadIdx.x; t < end; t += 256) {
        int e = (int)(t >> fshift);
        int f = (int)(t & (F - 1));
        u32 w = __builtin_nontemporal_load(part + e);
        int lo = 0, hi = NBUCK;   // invariant: bb[lo] <= e < bb[hi]
#pragma unroll
        for (int s = 0; s < 10; ++s) {
            int mid = (lo + hi) >> 1;
            if (bb[mid] <= (u32)e) lo = mid; else hi = mid;
        }
        int src = lo * RB + (int)(w >> 17);
        int dst = (int)(w & 0x1FFFFu);
        atomicAdd(agg + (size_t)dst * F + f, h[(size_t)src * F + f]);
    }
}

// ---- dense transforms ----

__global__ void xw16_kernel(const float* __restrict__ x, const float* __restrict__ W,
                            const float* __restrict__ norm_src,
                            float* __restrict__ h, int n) {
    __shared__ float Ws[256];
    int t = threadIdx.x;
    if (t < 256) Ws[t] = W[t];
    __syncthreads();
    int i = blockIdx.x * blockDim.x + t;
    if (i >= n) return;
    float xi[16];
    const float4* xp = reinterpret_cast<const float4*>(x + (size_t)i * 16);
    float4 v;
    v = xp[0]; xi[0]=v.x; xi[1]=v.y; xi[2]=v.z; xi[3]=v.w;
    v = xp[1]; xi[4]=v.x; xi[5]=v.y; xi[6]=v.z; xi[7]=v.w;
    v = xp[2]; xi[8]=v.x; xi[9]=v.y; xi[10]=v.z; xi[11]=v.w;
    v = xp[3]; xi[12]=v.x; xi[13]=v.y; xi[14]=v.z; xi[15]=v.w;
    float ns = norm_src[i];
    float o[16];
#pragma unroll
    for (int j = 0; j < 16; ++j) {
        float acc = 0.f;
#pragma unroll
        for (int k = 0; k < 16; ++k) acc = fmaf(xi[k], Ws[k * 16 + j], acc);
        o[j] = acc * ns;
    }
    float4* hp = reinterpret_cast<float4*>(h + (size_t)i * 16);
    hp[0] = make_float4(o[0], o[1], o[2], o[3]);
    hp[1] = make_float4(o[4], o[5], o[6], o[7]);
    hp[2] = make_float4(o[8], o[9], o[10], o[11]);
    hp[3] = make_float4(o[12], o[13], o[14], o[15]);
}

__global__ void xw8_kernel(const float* __restrict__ x, const float* __restrict__ W,
                           const float* __restrict__ norm_src,
                           float* __restrict__ h, int n) {
    __shared__ float Ws[128];
    int t = threadIdx.x;
    if (t < 128) Ws[t] = W[t];
    __syncthreads();
    int i = blockIdx.x * blockDim.x + t;
    if (i >= n) return;
    float xi[16];
    const float4* xp = reinterpret_cast<const float4*>(x + (size_t)i * 16);
    float4 v;
    v = xp[0]; xi[0]=v.x; xi[1]=v.y; xi[2]=v.z; xi[3]=v.w;
    v = xp[1]; xi[4]=v.x; xi[5]=v.y; xi[6]=v.z; xi[7]=v.w;
    v = xp[2]; xi[8]=v.x; xi[9]=v.y; xi[10]=v.z; xi[11]=v.w;
    v = xp[3]; xi[12]=v.x; xi[13]=v.y; xi[14]=v.z; xi[15]=v.w;
    float ns = norm_src[i];
    float o[8];
#pragma unroll
    for (int j = 0; j < 8; ++j) {
        float acc = 0.f;
#pragma unroll
        for (int k = 0; k < 16; ++k) acc = fmaf(xi[k], Ws[k * 8 + j], acc);
        o[j] = acc * ns;
    }
    float4* hp = reinterpret_cast<float4*>(h + (size_t)i * 8);
    hp[0] = make_float4(o[0], o[1], o[2], o[3]);
    hp[1] = make_float4(o[4], o[5], o[6], o[7]);
}

// out = ((agg + h_self) * norm_dst + b), optional relu (elementwise, in-place ok)
template <int F, bool RELU>
__global__ void combine_kernel(const float* __restrict__ agg, const float* __restrict__ h,
                               const float* __restrict__ norm_dst,
                               const float* __restrict__ b,
                               float* __restrict__ out, int n) {
    int t = blockIdx.x * 256 + threadIdx.x;
    if (t >= n * F) return;
    int i = t / F;
    int f = t % F;
    float v = (agg[t] + h[t]) * norm_dst[i] + b[f];
    if (RELU) v = fmaxf(v, 0.f);
    out[t] = v;
}

// ---- fallback (n != 100000 or small ws): scattered-atomic path ----

__global__ void init_deg_kernel(float* __restrict__ a, float* __restrict__ b, int n) {
    int i = blockIdx.x * 256 + threadIdx.x;
    if (i < n) { a[i] = 1.0f; b[i] = 1.0f; }
}
__global__ void count_deg_kernel(const int* __restrict__ src, const int* __restrict__ dst,
                                 float* __restrict__ dego, float* __restrict__ degi, int nE) {
    int e = blockIdx.x * 256 + threadIdx.x;
    if (e < nE) { atomicAdd(dego + src[e], 1.0f); atomicAdd(degi + dst[e], 1.0f); }
}
__global__ void rsqrt_kernel(float* __restrict__ a, float* __restrict__ b, int n) {
    int i = blockIdx.x * 256 + threadIdx.x;
    if (i < n) { a[i] = rsqrtf(a[i]); b[i] = rsqrtf(b[i]); }
}
template <int F>
__global__ void scatter_kernel(const int* __restrict__ src, const int* __restrict__ dst,
                               const float* __restrict__ h, float* __restrict__ agg,
                               int nE) {
    long long t = (long long)blockIdx.x * blockDim.x + threadIdx.x;
    if (t >= (long long)nE * F) return;
    int e = (int)(t / F);
    int f = (int)(t % F);
    atomicAdd(agg + (size_t)dst[e] * F + f, h[(size_t)src[e] * F + f]);
}

extern "C" void kernel_launch(void* const* d_in, const int* in_sizes, int n_in,
                              void* d_out, int out_size, void* d_ws, size_t ws_size,
                              hipStream_t stream) {
    const float* x  = (const float*)d_in[0];
    const float* W1 = (const float*)d_in[1];
    const float* b1 = (const float*)d_in[2];
    const float* W2 = (const float*)d_in[3];
    const float* b2 = (const float*)d_in[4];
    const int*   ei = (const int*)d_in[5];

    const int n  = in_sizes[0] / F1;   // 100000
    const int nE = in_sizes[5] / 2;    // 3200000
    const int* src = ei;
    const int* dst = ei + nE;

    const size_t na = ((size_t)n + 63) & ~(size_t)63;
    const int B = 256;
    dim3 blk(B);
    int gN   = (int)((n + B - 1) / B);
    int gNF1 = (int)((n * (size_t)F1 + B - 1) / B);
    int gNF2 = (int)((n * (size_t)F2 + B - 1) / B);

    // fast-path workspace layout
    float* norm_src = (float*)d_ws;                  // [na]
    float* norm_dst = norm_src + na;                 // [na]
    u32*   bbase    = (u32*)(norm_dst + na);         // [1024]
    u32*   bcur     = bbase + 1024;                  // [1024]
    u32*   bcnt     = bcur + 1024;                   // [1024]
    u32*   part     = bcnt + 1024;                   // [nE]
    float* bufA     = (float*)(part + nE);           // [na*16] h1' then out1
    float* bufB     = bufA + na * F1;                // [na*16] agg1; then h2 | agg2
    u32*   partial  = part;                          // NB_HIST*HIST_U32 overlays part+buf
    size_t need = ((size_t)2 * na + 3 * 1024 + (size_t)nE + 32 * na) * 4;
    size_t need_hist = ((size_t)2 * na + 3 * 1024) * 4 + (size_t)NB_HIST * HIST_U32 * 4;
    if (need_hist > need) need = need_hist;

    if (n == HIST_N && ws_size >= need) {
        int per_hist = (nE + NB_HIST - 1) / NB_HIST;
        int per_p2   = (nE + P2B - 1) / P2B;
        int gM = (HIST_U32 + B - 1) / B;

        // norm_dst via u8-hist on dst (partial overlays part/buf region; done
        // before partition writes part)
        hist_kernel<<<NB_HIST, blk, 0, stream>>>(dst, partial, nE, per_hist);
        merge_norm_kernel<<<gM, blk, 0, stream>>>(partial, norm_dst);

        // counting sort of edges by src bucket (src>>7)
        hipMemsetAsync(bcnt, 0, NBUCK * sizeof(u32), stream);
        bucket_count_kernel<<<P2B, blk, 0, stream>>>(src, bcnt, nE);
        bucket_scan_kernel<<<1, 1024, 0, stream>>>(bcnt, bbase, bcur);
        partition_kernel<<<P2B, blk, 0, stream>>>(src, dst, part, bcur, nE, per_p2);
        norm_src_kernel<<<NBUCK, blk, 0, stream>>>(part, bbase, norm_src, n);

        // layer 1: h1' = xW1*norm_src; agg1 = A^T h1'; out1 = relu((agg1+h1')*nd+b1)
        xw16_kernel<<<gN, blk, 0, stream>>>(x, W1, norm_src, bufA, n);
        hipMemsetAsync(bufB, 0, (size_t)n * F1 * sizeof(float), stream);
        scatter_bucketed_kernel<F1><<<SCB, blk, 0, stream>>>(part, bbase, bufA, bufB, nE);
        combine_kernel<F1, true><<<gNF1, blk, 0, stream>>>(bufB, bufA, norm_dst, b1,
                                                           bufA, n);  // out1 -> bufA

        // layer 2: h2 = out1*W2*norm_src (bufB low half); agg2 = bufB high half
        float* h2   = bufB;
        float* agg2 = bufB + na * F2;
        xw8_kernel<<<gN, blk, 0, stream>>>(bufA, W2, norm_src, h2, n);
        hipMemsetAsync(agg2, 0, (size_t)n * F2 * sizeof(float), stream);
        scatter_bucketed_kernel<F2><<<SCB, blk, 0, stream>>>(part, bbase, h2, agg2, nE);
        combine_kernel<F2, false><<<gNF2, blk, 0, stream>>>(agg2, h2, norm_dst, b2,
                                                            (float*)d_out, n);
    } else {
        // fallback: scattered atomics (fits 13.7 MB ws)
        float* fnorm_src = (float*)d_ws;
        float* fnorm_dst = fnorm_src + na;
        float* fbufA     = fnorm_dst + na;
        float* fbufB     = fbufA + na * F1;
        int gE   = (nE + B - 1) / B;
        int gEF1 = (int)(((long long)nE * F1 + B - 1) / B);
        int gEF2 = (int)(((long long)nE * F2 + B - 1) / B);
        init_deg_kernel<<<gN, blk, 0, stream>>>(fnorm_src, fnorm_dst, n);
        count_deg_kernel<<<gE, blk, 0, stream>>>(src, dst, fnorm_src, fnorm_dst, nE);
        rsqrt_kernel<<<gN, blk, 0, stream>>>(fnorm_src, fnorm_dst, n);
        xw16_kernel<<<gN, blk, 0, stream>>>(x, W1, fnorm_src, fbufA, n);
        hipMemsetAsync(fbufB, 0, (size_t)n * F1 * sizeof(float), stream);
        scatter_kernel<F1><<<gEF1, blk, 0, stream>>>(src, dst, fbufA, fbufB, nE);
        combine_kernel<F1, true><<<gNF1, blk, 0, stream>>>(fbufB, fbufA, fnorm_dst, b1, fbufA, n);
        xw8_kernel<<<gN, blk, 0, stream>>>(fbufA, W2, fnorm_src, fbufB, n);
        hipMemsetAsync(fbufB + na * F2, 0, (size_t)n * F2 * sizeof(float), stream);
        scatter_kernel<F2><<<gEF2, blk, 0, stream>>>(src, dst, fbufB, fbufB + na * F2, nE);
        combine_kernel<F2, false><<<gNF2, blk, 0, stream>>>(fbufB + na * F2, fbufB, fnorm_dst,
                                                            b2, (float*)d_out, n);
    }
}